// Round 1
// baseline (2934.597 us; speedup 1.0000x reference)
//
#include <hip/hip_runtime.h>

// Swin block: LN1 -> shift+window -> qkv GEMM -> windowed attn -> proj GEMM(+scatter+residual)
//          -> LN2 -> fc1 GEMM(+GELU) -> fc2 GEMM(+residual)
// B=64, H=W=56, C=384, WS=7, SS=3, NH=12, hd=32, N=49, nW=64, B_=4096, M=200704

typedef __bf16 bf16x8 __attribute__((ext_vector_type(8)));
typedef float  f32x4  __attribute__((ext_vector_type(4)));

__device__ __forceinline__ unsigned short f2bf(float f) {
    unsigned int u = __builtin_bit_cast(unsigned int, f);
    u += 0x7fffu + ((u >> 16) & 1u);   // RNE
    return (unsigned short)(u >> 16);
}
__device__ __forceinline__ float bf2f(unsigned short h) {
    return __builtin_bit_cast(float, (unsigned int)h << 16);
}

// ---------------- weight transpose + cast: W[K,N] f32 -> Bt[N,K] bf16 ----------------
__global__ __launch_bounds__(256) void k_transpose(const float* __restrict__ W,
                                                   unsigned short* __restrict__ Bt,
                                                   int K, int N) {
    int idx = blockIdx.x * 256 + threadIdx.x;
    if (idx >= N * K) return;
    int n = idx / K, k = idx - n * K;
    Bt[idx] = f2bf(W[(long)k * N + n]);
}

// ---------------- LN1 + cyclic shift(-3,-3) + window partition ----------------
// out row order: ((b*64 + wi)*49 + t), wi = wr*8+wc, t = th*7+tw
__global__ __launch_bounds__(256) void k_ln1(const float* __restrict__ x,
                                             const float* __restrict__ g,
                                             const float* __restrict__ bb,
                                             unsigned short* __restrict__ xw) {
    int wid = threadIdx.x >> 6, lane = threadIdx.x & 63;
    int tok = blockIdx.x * 4 + wid;                 // < 200704
    int t  = tok % 49; int b_ = tok / 49;
    int wi = b_ & 63;  int b  = b_ >> 6;
    int th = t / 7, tw = t - th * 7;
    int hs = (wi >> 3) * 7 + th + 3; if (hs >= 56) hs -= 56;   // shifted -> source coord
    int vs = (wi & 7) * 7 + tw + 3;  if (vs >= 56) vs -= 56;
    const float* row = x + ((long)b * 3136 + hs * 56 + vs) * 384;
    float v[6]; float s = 0.f;
    #pragma unroll
    for (int i = 0; i < 6; ++i) { v[i] = row[lane + 64 * i]; s += v[i]; }
    #pragma unroll
    for (int o = 32; o; o >>= 1) s += __shfl_xor(s, o);
    float mean = s * (1.f / 384.f);
    float q = 0.f;
    #pragma unroll
    for (int i = 0; i < 6; ++i) { float d = v[i] - mean; q += d * d; }
    #pragma unroll
    for (int o = 32; o; o >>= 1) q += __shfl_xor(q, o);
    float inv = rsqrtf(q * (1.f / 384.f) + 1e-5f);
    unsigned short* orow = xw + (long)tok * 384;
    #pragma unroll
    for (int i = 0; i < 6; ++i) {
        int c = lane + 64 * i;
        orow[c] = f2bf((v[i] - mean) * inv * g[c] + bb[c]);
    }
}

// ---------------- LN2 over token-ordered rows ----------------
__global__ __launch_bounds__(256) void k_ln2(const float* __restrict__ xin,
                                             const float* __restrict__ g,
                                             const float* __restrict__ bb,
                                             unsigned short* __restrict__ o) {
    int wid = threadIdx.x >> 6, lane = threadIdx.x & 63;
    int tok = blockIdx.x * 4 + wid;
    const float* row = xin + (long)tok * 384;
    float v[6]; float s = 0.f;
    #pragma unroll
    for (int i = 0; i < 6; ++i) { v[i] = row[lane + 64 * i]; s += v[i]; }
    #pragma unroll
    for (int off = 32; off; off >>= 1) s += __shfl_xor(s, off);
    float mean = s * (1.f / 384.f);
    float q = 0.f;
    #pragma unroll
    for (int i = 0; i < 6; ++i) { float d = v[i] - mean; q += d * d; }
    #pragma unroll
    for (int off = 32; off; off >>= 1) q += __shfl_xor(q, off);
    float inv = rsqrtf(q * (1.f / 384.f) + 1e-5f);
    unsigned short* orow = o + (long)tok * 384;
    #pragma unroll
    for (int i = 0; i < 6; ++i) {
        int c = lane + 64 * i;
        orow[c] = f2bf((v[i] - mean) * inv * g[c] + bb[c]);
    }
}

// ---------------- windowed attention: 1 wave per (window, head) ----------------
// qkv chunk: [512*49, 1152] bf16; q col h*32+d, k col 384+h*32+d, v col 768+h*32+d
__global__ __launch_bounds__(64) void k_attn(const unsigned short* __restrict__ qkv,
                                             const float* __restrict__ rpb,     // [169,12]
                                             unsigned short* __restrict__ aout, // [512*49,384]
                                             int win_base) {
    __shared__ float Ks[49][32];
    __shared__ float Vs[49][32];
    int h  = blockIdx.x;
    int lw = blockIdx.y;
    int wi = (win_base + lw) & 63;
    int lane = threadIdx.x;
    const unsigned short* base = qkv + (long)lw * 49 * 1152;
    for (int t = lane; t < 1568; t += 64) {
        int j = t >> 5, d = t & 31;
        Ks[j][d] = bf2f(base[j * 1152 + 384 + h * 32 + d]);
        Vs[j][d] = bf2f(base[j * 1152 + 768 + h * 32 + d]);
    }
    __syncthreads();
    if (lane >= 49) return;
    float qv[32];
    {
        const unsigned short* qrow = base + (long)lane * 1152 + h * 32;
        #pragma unroll
        for (int d = 0; d < 32; ++d) qv[d] = bf2f(qrow[d]);
    }
    int wr = wi >> 3, wc = wi & 7;
    int qth = lane / 7, qtw = lane - qth * 7;
    int rHq = (wr < 7) ? 0 : ((qth < 4) ? 1 : 2);   // shift-mask region along H
    int rWq = (wc < 7) ? 0 : ((qtw < 4) ? 1 : 2);
    float sarr[49];
    float mx = -3.0e38f;
    #pragma unroll
    for (int j = 0; j < 49; ++j) {
        const f32x4* kr = (const f32x4*)(&Ks[j][0]);
        float acc = 0.f;
        #pragma unroll
        for (int d4 = 0; d4 < 8; ++d4) {
            f32x4 kk = kr[d4];
            acc += qv[4*d4+0]*kk[0] + qv[4*d4+1]*kk[1] + qv[4*d4+2]*kk[2] + qv[4*d4+3]*kk[3];
        }
        acc *= 0.17677669529663687f;               // hd^-0.5
        int jth = j / 7, jtw = j - jth * 7;
        acc += rpb[((qth - jth + 6) * 13 + (qtw - jtw + 6)) * 12 + h];
        int rHj = (wr < 7) ? 0 : ((jth < 4) ? 1 : 2);
        int rWj = (wc < 7) ? 0 : ((jtw < 4) ? 1 : 2);
        if ((rHj != rHq) | (rWj != rWq)) acc -= 100.f;
        sarr[j] = acc;
        mx = fmaxf(mx, acc);
    }
    float sum = 0.f;
    #pragma unroll
    for (int j = 0; j < 49; ++j) { sarr[j] = __expf(sarr[j] - mx); sum += sarr[j]; }
    float inv = 1.f / sum;
    float o[32];
    #pragma unroll
    for (int d = 0; d < 32; ++d) o[d] = 0.f;
    #pragma unroll
    for (int j = 0; j < 49; ++j) {
        float p = sarr[j] * inv;
        const f32x4* vr = (const f32x4*)(&Vs[j][0]);
        #pragma unroll
        for (int d4 = 0; d4 < 8; ++d4) {
            f32x4 vv = vr[d4];
            o[4*d4+0] += p * vv[0]; o[4*d4+1] += p * vv[1];
            o[4*d4+2] += p * vv[2]; o[4*d4+3] += p * vv[3];
        }
    }
    unsigned short* orow = aout + ((long)lw * 49 + lane) * 384 + h * 32;
    #pragma unroll
    for (int d = 0; d < 32; ++d) orow[d] = f2bf(o[d]);
}

// ---------------- bf16 MFMA GEMM, 128x128 tile, BK=64, 4 waves ----------------
// A[M,K] bf16 rm, Bt[N,K] bf16 rm (B transposed). XOR slot-swizzle on LDS (both sides).
// EPI: 0 = bf16 out, 1 = bf16 out + exact GELU, 2 = f32 scatter (un-window+un-roll)+res,
//      3 = f32 out + res (row-major, rows m_base+row)
template<int EPI>
__global__ __launch_bounds__(256) void k_gemm(
    const unsigned short* __restrict__ A,
    const unsigned short* __restrict__ Bt,
    const float* __restrict__ bias,
    unsigned short* outb, float* outf, const float* res,
    int M, int N, int K, int m_base)
{
    __shared__ unsigned short As[128][64];
    __shared__ unsigned short Bs[128][64];
    int m0 = blockIdx.y << 7, n0 = blockIdx.x << 7;
    int tid = threadIdx.x, wid = tid >> 6, lane = tid & 63;
    int wr = wid >> 1, wc = wid & 1;
    f32x4 acc[4][4];
    #pragma unroll
    for (int i = 0; i < 4; ++i)
        #pragma unroll
        for (int j = 0; j < 4; ++j)
            acc[i][j] = (f32x4){0.f, 0.f, 0.f, 0.f};

    // staging: each wave stages 32 rows of A and 32 rows of Bt per K-step.
    // LDS slot s of row r holds global k-slot s^(r&7)  (source pre-swizzle, m173 pattern)
    int lrow = lane >> 3;
    int lcol = (lane & 7) ^ lrow;
    const unsigned short* Ag = A  + (long)(m0 + wid * 32 + lrow) * K + lcol * 8;
    const unsigned short* Bg = Bt + (long)(n0 + wid * 32 + lrow) * K + lcol * 8;

    for (int k0 = 0; k0 < K; k0 += 64) {
        #pragma unroll
        for (int c = 0; c < 4; ++c) {
            __builtin_amdgcn_global_load_lds(
                (__attribute__((address_space(1))) void*)(Ag + k0 + c * 8 * K),
                (__attribute__((address_space(3))) void*)(&As[wid * 32 + c * 8][0]), 16, 0, 0);
            __builtin_amdgcn_global_load_lds(
                (__attribute__((address_space(1))) void*)(Bg + k0 + c * 8 * K),
                (__attribute__((address_space(3))) void*)(&Bs[wid * 32 + c * 8][0]), 16, 0, 0);
        }
        __syncthreads();
        #pragma unroll
        for (int kk = 0; kk < 2; ++kk) {
            bf16x8 af[4], bfr[4];
            #pragma unroll
            for (int mi = 0; mi < 4; ++mi) {
                int r = wr * 64 + mi * 16 + (lane & 15);
                int slot = (kk * 4 + (lane >> 4)) ^ (r & 7);
                af[mi] = *reinterpret_cast<const bf16x8*>(&As[r][slot * 8]);
            }
            #pragma unroll
            for (int ni = 0; ni < 4; ++ni) {
                int r = wc * 64 + ni * 16 + (lane & 15);
                int slot = (kk * 4 + (lane >> 4)) ^ (r & 7);
                bfr[ni] = *reinterpret_cast<const bf16x8*>(&Bs[r][slot * 8]);
            }
            #pragma unroll
            for (int mi = 0; mi < 4; ++mi)
                #pragma unroll
                for (int ni = 0; ni < 4; ++ni)
                    acc[mi][ni] = __builtin_amdgcn_mfma_f32_16x16x32_bf16(
                        af[mi], bfr[ni], acc[mi][ni], 0, 0, 0);
        }
        __syncthreads();
    }

    #pragma unroll
    for (int mi = 0; mi < 4; ++mi) {
        #pragma unroll
        for (int ni = 0; ni < 4; ++ni) {
            int col = n0 + wc * 64 + ni * 16 + (lane & 15);
            float bv = bias[col];
            #pragma unroll
            for (int i = 0; i < 4; ++i) {
                int row = m0 + wr * 64 + mi * 16 + (lane >> 4) * 4 + i;
                float v = acc[mi][ni][i] + bv;
                if constexpr (EPI == 0) {
                    outb[(long)row * N + col] = f2bf(v);
                } else if constexpr (EPI == 1) {
                    outb[(long)row * N + col] = f2bf(0.5f * v * (1.f + erff(v * 0.70710678f)));
                } else if constexpr (EPI == 2) {
                    int mg = m_base + row;
                    int b = mg / 3136; int rem = mg - b * 3136;
                    int wi = rem / 49; int t = rem - wi * 49;
                    int th = t / 7, tw = t - th * 7;
                    int hh = (wi >> 3) * 7 + th + 3; if (hh >= 56) hh -= 56;
                    int ww = (wi & 7) * 7 + tw + 3;  if (ww >= 56) ww -= 56;
                    long oidx = ((long)b * 3136 + hh * 56 + ww) * 384 + col;
                    outf[oidx] = v + res[oidx];
                } else {
                    long oidx = (long)(m_base + row) * 384 + col;
                    outf[oidx] = v + res[oidx];
                }
            }
        }
    }
}

extern "C" void kernel_launch(void* const* d_in, const int* in_sizes, int n_in,
                              void* d_out, int out_size, void* d_ws, size_t ws_size,
                              hipStream_t stream) {
    (void)in_sizes; (void)n_in; (void)out_size; (void)ws_size;
    const float* x     = (const float*)d_in[0];
    const float* n1g   = (const float*)d_in[1];
    const float* n1b   = (const float*)d_in[2];
    const float* qkvw  = (const float*)d_in[3];
    const float* qkvb  = (const float*)d_in[4];
    const float* rpb   = (const float*)d_in[5];
    const float* projw = (const float*)d_in[6];
    const float* projb = (const float*)d_in[7];
    const float* n2g   = (const float*)d_in[8];
    const float* n2b   = (const float*)d_in[9];
    const float* fc1w  = (const float*)d_in[10];
    const float* fc1b  = (const float*)d_in[11];
    const float* fc2w  = (const float*)d_in[12];
    const float* fc2b  = (const float*)d_in[13];
    float* out = (float*)d_out;

    char* ws = (char*)d_ws;
    size_t off = 0;
    auto alloc = [&](size_t bytes) { char* p = ws + off; off += (bytes + 255) & ~(size_t)255; return p; };
    unsigned short* BtQ  = (unsigned short*)alloc((size_t)1152 * 384 * 2);
    unsigned short* BtP  = (unsigned short*)alloc((size_t)384 * 384 * 2);
    unsigned short* Bt1  = (unsigned short*)alloc((size_t)1536 * 384 * 2);
    unsigned short* Bt2  = (unsigned short*)alloc((size_t)384 * 1536 * 2);
    unsigned short* xw   = (unsigned short*)alloc((size_t)200704 * 384 * 2);  // xw, reused as h2
    unsigned short* bufB = (unsigned short*)alloc((size_t)25088 * 1536 * 2);  // qkv chunk / fc1 chunk
    unsigned short* attb = (unsigned short*)alloc((size_t)25088 * 384 * 2);   // attn-out chunk

    k_transpose<<<dim3((1152 * 384 + 255) / 256), 256, 0, stream>>>(qkvw, BtQ, 384, 1152);
    k_transpose<<<dim3((384 * 384 + 255) / 256), 256, 0, stream>>>(projw, BtP, 384, 384);
    k_transpose<<<dim3((1536 * 384 + 255) / 256), 256, 0, stream>>>(fc1w, Bt1, 384, 1536);
    k_transpose<<<dim3((384 * 1536 + 255) / 256), 256, 0, stream>>>(fc2w, Bt2, 1536, 384);

    k_ln1<<<dim3(50176), 256, 0, stream>>>(x, n1g, n1b, xw);

    // attention phase: 8 chunks of 512 windows (25088 rows)
    for (int c = 0; c < 8; ++c) {
        const unsigned short* Ax = xw + (size_t)c * 25088 * 384;
        k_gemm<0><<<dim3(9, 196), 256, 0, stream>>>(Ax, BtQ, qkvb, bufB, nullptr, nullptr,
                                                    25088, 1152, 384, 0);
        k_attn<<<dim3(12, 512), 64, 0, stream>>>(bufB, rpb, attb, c * 512);
        k_gemm<2><<<dim3(3, 196), 256, 0, stream>>>(attb, BtP, projb, nullptr, out, x,
                                                    25088, 384, 384, c * 25088);
    }

    k_ln2<<<dim3(50176), 256, 0, stream>>>(out, n2g, n2b, xw);

    // MLP phase
    for (int c = 0; c < 8; ++c) {
        const unsigned short* Ah = xw + (size_t)c * 25088 * 384;
        k_gemm<1><<<dim3(12, 196), 256, 0, stream>>>(Ah, Bt1, fc1b, bufB, nullptr, nullptr,
                                                     25088, 1536, 384, 0);
        k_gemm<3><<<dim3(3, 196), 256, 0, stream>>>(bufB, Bt2, fc2b, nullptr, out, out,
                                                    25088, 384, 1536, c * 25088);
    }
}

// Round 2
// 2751.583 us; speedup vs baseline: 1.0665x; 1.0665x over previous
//
#include <hip/hip_runtime.h>

// Swin block: LN1 -> shift+window -> qkv GEMM -> windowed attn -> proj GEMM(+scatter+residual)
//          -> LN2 -> fc1 GEMM(+GELU) -> fc2 GEMM(+residual)
// B=64, H=W=56, C=384, WS=7, SS=3, NH=12, hd=32, N=49, nW=64, B_=4096, M=200704
// R2: un-chunked pipeline (runtime ws_size check), bijective XCD swizzle on GEMM tiles,
//     vectorized attn output stores.

typedef __bf16 bf16x8 __attribute__((ext_vector_type(8)));
typedef float  f32x4  __attribute__((ext_vector_type(4)));
typedef unsigned short u16x8 __attribute__((ext_vector_type(8)));

__device__ __forceinline__ unsigned short f2bf(float f) {
    unsigned int u = __builtin_bit_cast(unsigned int, f);
    u += 0x7fffu + ((u >> 16) & 1u);   // RNE
    return (unsigned short)(u >> 16);
}
__device__ __forceinline__ float bf2f(unsigned short h) {
    return __builtin_bit_cast(float, (unsigned int)h << 16);
}

// ---------------- weight transpose + cast: W[K,N] f32 -> Bt[N,K] bf16 ----------------
__global__ __launch_bounds__(256) void k_transpose(const float* __restrict__ W,
                                                   unsigned short* __restrict__ Bt,
                                                   int K, int N) {
    int idx = blockIdx.x * 256 + threadIdx.x;
    if (idx >= N * K) return;
    int n = idx / K, k = idx - n * K;
    Bt[idx] = f2bf(W[(long)k * N + n]);
}

// ---------------- LN1 + cyclic shift(-3,-3) + window partition ----------------
// out row order: ((b*64 + wi)*49 + t), wi = wr*8+wc, t = th*7+tw
__global__ __launch_bounds__(256) void k_ln1(const float* __restrict__ x,
                                             const float* __restrict__ g,
                                             const float* __restrict__ bb,
                                             unsigned short* __restrict__ xw) {
    int wid = threadIdx.x >> 6, lane = threadIdx.x & 63;
    int tok = blockIdx.x * 4 + wid;                 // < 200704
    int t  = tok % 49; int b_ = tok / 49;
    int wi = b_ & 63;  int b  = b_ >> 6;
    int th = t / 7, tw = t - th * 7;
    int hs = (wi >> 3) * 7 + th + 3; if (hs >= 56) hs -= 56;   // shifted -> source coord
    int vs = (wi & 7) * 7 + tw + 3;  if (vs >= 56) vs -= 56;
    const float* row = x + ((long)b * 3136 + hs * 56 + vs) * 384;
    float v[6]; float s = 0.f;
    #pragma unroll
    for (int i = 0; i < 6; ++i) { v[i] = row[lane + 64 * i]; s += v[i]; }
    #pragma unroll
    for (int o = 32; o; o >>= 1) s += __shfl_xor(s, o);
    float mean = s * (1.f / 384.f);
    float q = 0.f;
    #pragma unroll
    for (int i = 0; i < 6; ++i) { float d = v[i] - mean; q += d * d; }
    #pragma unroll
    for (int o = 32; o; o >>= 1) q += __shfl_xor(q, o);
    float inv = rsqrtf(q * (1.f / 384.f) + 1e-5f);
    unsigned short* orow = xw + (long)tok * 384;
    #pragma unroll
    for (int i = 0; i < 6; ++i) {
        int c = lane + 64 * i;
        orow[c] = f2bf((v[i] - mean) * inv * g[c] + bb[c]);
    }
}

// ---------------- LN2 over token-ordered rows ----------------
__global__ __launch_bounds__(256) void k_ln2(const float* __restrict__ xin,
                                             const float* __restrict__ g,
                                             const float* __restrict__ bb,
                                             unsigned short* __restrict__ o) {
    int wid = threadIdx.x >> 6, lane = threadIdx.x & 63;
    int tok = blockIdx.x * 4 + wid;
    const float* row = xin + (long)tok * 384;
    float v[6]; float s = 0.f;
    #pragma unroll
    for (int i = 0; i < 6; ++i) { v[i] = row[lane + 64 * i]; s += v[i]; }
    #pragma unroll
    for (int off = 32; off; off >>= 1) s += __shfl_xor(s, off);
    float mean = s * (1.f / 384.f);
    float q = 0.f;
    #pragma unroll
    for (int i = 0; i < 6; ++i) { float d = v[i] - mean; q += d * d; }
    #pragma unroll
    for (int off = 32; off; off >>= 1) q += __shfl_xor(q, off);
    float inv = rsqrtf(q * (1.f / 384.f) + 1e-5f);
    unsigned short* orow = o + (long)tok * 384;
    #pragma unroll
    for (int i = 0; i < 6; ++i) {
        int c = lane + 64 * i;
        orow[c] = f2bf((v[i] - mean) * inv * g[c] + bb[c]);
    }
}

// ---------------- windowed attention: 1 wave per (window, head) ----------------
// qkv rows: [nwin*49, 1152] bf16; q col h*32+d, k col 384+h*32+d, v col 768+h*32+d
__global__ __launch_bounds__(64) void k_attn(const unsigned short* __restrict__ qkv,
                                             const float* __restrict__ rpb,     // [169,12]
                                             unsigned short* __restrict__ aout, // [nwin*49,384]
                                             int win_base) {
    __shared__ float Ks[49][32];
    __shared__ float Vs[49][32];
    int h  = blockIdx.x;
    int lw = blockIdx.y;
    int wi = (win_base + lw) & 63;
    int lane = threadIdx.x;
    const unsigned short* base = qkv + (long)lw * 49 * 1152;
    // column-parallel staging: consecutive lanes -> consecutive d (conflict-free LDS writes)
    for (int t = lane; t < 1568; t += 64) {
        int j = t >> 5, d = t & 31;
        Ks[j][d] = bf2f(base[j * 1152 + 384 + h * 32 + d]);
        Vs[j][d] = bf2f(base[j * 1152 + 768 + h * 32 + d]);
    }
    __syncthreads();
    if (lane >= 49) return;
    float qv[32];
    {
        const unsigned short* qrow = base + (long)lane * 1152 + h * 32;
        #pragma unroll
        for (int p = 0; p < 4; ++p) {
            u16x8 qq = *reinterpret_cast<const u16x8*>(qrow + p * 8);
            #pragma unroll
            for (int e = 0; e < 8; ++e) qv[p * 8 + e] = bf2f(qq[e]);
        }
    }
    int wr = wi >> 3, wc = wi & 7;
    int qth = lane / 7, qtw = lane - qth * 7;
    int rHq = (wr < 7) ? 0 : ((qth < 4) ? 1 : 2);   // shift-mask region along H
    int rWq = (wc < 7) ? 0 : ((qtw < 4) ? 1 : 2);
    float sarr[49];
    float mx = -3.0e38f;
    #pragma unroll
    for (int j = 0; j < 49; ++j) {
        const f32x4* kr = (const f32x4*)(&Ks[j][0]);
        float acc = 0.f;
        #pragma unroll
        for (int d4 = 0; d4 < 8; ++d4) {
            f32x4 kk = kr[d4];
            acc += qv[4*d4+0]*kk[0] + qv[4*d4+1]*kk[1] + qv[4*d4+2]*kk[2] + qv[4*d4+3]*kk[3];
        }
        acc *= 0.17677669529663687f;               // hd^-0.5
        int jth = j / 7, jtw = j - jth * 7;
        acc += rpb[((qth - jth + 6) * 13 + (qtw - jtw + 6)) * 12 + h];
        int rHj = (wr < 7) ? 0 : ((jth < 4) ? 1 : 2);
        int rWj = (wc < 7) ? 0 : ((jtw < 4) ? 1 : 2);
        if ((rHj != rHq) | (rWj != rWq)) acc -= 100.f;
        sarr[j] = acc;
        mx = fmaxf(mx, acc);
    }
    float sum = 0.f;
    #pragma unroll
    for (int j = 0; j < 49; ++j) { sarr[j] = __expf(sarr[j] - mx); sum += sarr[j]; }
    float inv = 1.f / sum;
    float o[32];
    #pragma unroll
    for (int d = 0; d < 32; ++d) o[d] = 0.f;
    #pragma unroll
    for (int j = 0; j < 49; ++j) {
        float p = sarr[j] * inv;
        const f32x4* vr = (const f32x4*)(&Vs[j][0]);
        #pragma unroll
        for (int d4 = 0; d4 < 8; ++d4) {
            f32x4 vv = vr[d4];
            o[4*d4+0] += p * vv[0]; o[4*d4+1] += p * vv[1];
            o[4*d4+2] += p * vv[2]; o[4*d4+3] += p * vv[3];
        }
    }
    unsigned short* orow = aout + ((long)lw * 49 + lane) * 384 + h * 32;
    #pragma unroll
    for (int p = 0; p < 4; ++p) {
        u16x8 ov;
        #pragma unroll
        for (int e = 0; e < 8; ++e) ov[e] = f2bf(o[p * 8 + e]);
        *reinterpret_cast<u16x8*>(orow + p * 8) = ov;
    }
}

// ---------------- bf16 MFMA GEMM, 128x128 tile, BK=64, 4 waves ----------------
// A[M,K] bf16 rm, Bt[N,K] bf16 rm (B transposed). XOR slot-swizzle on LDS (both sides).
// Bijective XCD swizzle (m204) on flattened tile id.
// EPI: 0 = bf16 out, 1 = bf16 out + exact GELU, 2 = f32 scatter (un-window+un-roll)+res,
//      3 = f32 out + res (row-major, rows m_base+row)
template<int EPI>
__global__ __launch_bounds__(256) void k_gemm(
    const unsigned short* __restrict__ A,
    const unsigned short* __restrict__ Bt,
    const float* __restrict__ bias,
    unsigned short* outb, float* outf, const float* res,
    int M, int N, int K, int m_base)
{
    __shared__ unsigned short As[128][64];
    __shared__ unsigned short Bs[128][64];
    // ---- bijective XCD swizzle (m204): consecutive swz ids land on the same XCD ----
    int nwg = gridDim.x * gridDim.y;
    int bid = blockIdx.y * gridDim.x + blockIdx.x;
    int qq = nwg >> 3, rr = nwg & 7;
    int xcd = bid & 7, idx = bid >> 3;
    int swz = (xcd < rr) ? (xcd * (qq + 1) + idx) : (rr * (qq + 1) + (xcd - rr) * qq + idx);
    int m0 = (swz / gridDim.x) << 7;
    int n0 = (swz % gridDim.x) << 7;

    int tid = threadIdx.x, wid = tid >> 6, lane = tid & 63;
    int wr = wid >> 1, wc = wid & 1;
    f32x4 acc[4][4];
    #pragma unroll
    for (int i = 0; i < 4; ++i)
        #pragma unroll
        for (int j = 0; j < 4; ++j)
            acc[i][j] = (f32x4){0.f, 0.f, 0.f, 0.f};

    // staging: each wave stages 32 rows of A and 32 rows of Bt per K-step.
    // LDS slot s of row r holds global k-slot s^(r&7)  (source pre-swizzle, m173 pattern)
    int lrow = lane >> 3;
    int lcol = (lane & 7) ^ lrow;
    const unsigned short* Ag = A  + (long)(m0 + wid * 32 + lrow) * K + lcol * 8;
    const unsigned short* Bg = Bt + (long)(n0 + wid * 32 + lrow) * K + lcol * 8;

    for (int k0 = 0; k0 < K; k0 += 64) {
        #pragma unroll
        for (int c = 0; c < 4; ++c) {
            __builtin_amdgcn_global_load_lds(
                (__attribute__((address_space(1))) void*)(Ag + k0 + c * 8 * K),
                (__attribute__((address_space(3))) void*)(&As[wid * 32 + c * 8][0]), 16, 0, 0);
            __builtin_amdgcn_global_load_lds(
                (__attribute__((address_space(1))) void*)(Bg + k0 + c * 8 * K),
                (__attribute__((address_space(3))) void*)(&Bs[wid * 32 + c * 8][0]), 16, 0, 0);
        }
        __syncthreads();
        #pragma unroll
        for (int kk = 0; kk < 2; ++kk) {
            bf16x8 af[4], bfr[4];
            #pragma unroll
            for (int mi = 0; mi < 4; ++mi) {
                int r = wr * 64 + mi * 16 + (lane & 15);
                int slot = (kk * 4 + (lane >> 4)) ^ (r & 7);
                af[mi] = *reinterpret_cast<const bf16x8*>(&As[r][slot * 8]);
            }
            #pragma unroll
            for (int ni = 0; ni < 4; ++ni) {
                int r = wc * 64 + ni * 16 + (lane & 15);
                int slot = (kk * 4 + (lane >> 4)) ^ (r & 7);
                bfr[ni] = *reinterpret_cast<const bf16x8*>(&Bs[r][slot * 8]);
            }
            #pragma unroll
            for (int mi = 0; mi < 4; ++mi)
                #pragma unroll
                for (int ni = 0; ni < 4; ++ni)
                    acc[mi][ni] = __builtin_amdgcn_mfma_f32_16x16x32_bf16(
                        af[mi], bfr[ni], acc[mi][ni], 0, 0, 0);
        }
        __syncthreads();
    }

    #pragma unroll
    for (int mi = 0; mi < 4; ++mi) {
        #pragma unroll
        for (int ni = 0; ni < 4; ++ni) {
            int col = n0 + wc * 64 + ni * 16 + (lane & 15);
            float bv = bias[col];
            #pragma unroll
            for (int i = 0; i < 4; ++i) {
                int row = m0 + wr * 64 + mi * 16 + (lane >> 4) * 4 + i;
                float v = acc[mi][ni][i] + bv;
                if constexpr (EPI == 0) {
                    outb[(long)row * N + col] = f2bf(v);
                } else if constexpr (EPI == 1) {
                    outb[(long)row * N + col] = f2bf(0.5f * v * (1.f + erff(v * 0.70710678f)));
                } else if constexpr (EPI == 2) {
                    int mg = m_base + row;
                    int b = mg / 3136; int rem = mg - b * 3136;
                    int wi = rem / 49; int t = rem - wi * 49;
                    int th = t / 7, tw = t - th * 7;
                    int hh = (wi >> 3) * 7 + th + 3; if (hh >= 56) hh -= 56;
                    int ww = (wi & 7) * 7 + tw + 3;  if (ww >= 56) ww -= 56;
                    long oidx = ((long)b * 3136 + hh * 56 + ww) * 384 + col;
                    outf[oidx] = v + res[oidx];
                } else {
                    long oidx = (long)(m_base + row) * 384 + col;
                    outf[oidx] = v + res[oidx];
                }
            }
        }
    }
}

extern "C" void kernel_launch(void* const* d_in, const int* in_sizes, int n_in,
                              void* d_out, int out_size, void* d_ws, size_t ws_size,
                              hipStream_t stream) {
    (void)in_sizes; (void)n_in; (void)out_size;
    const float* x     = (const float*)d_in[0];
    const float* n1g   = (const float*)d_in[1];
    const float* n1b   = (const float*)d_in[2];
    const float* qkvw  = (const float*)d_in[3];
    const float* qkvb  = (const float*)d_in[4];
    const float* rpb   = (const float*)d_in[5];
    const float* projw = (const float*)d_in[6];
    const float* projb = (const float*)d_in[7];
    const float* n2g   = (const float*)d_in[8];
    const float* n2b   = (const float*)d_in[9];
    const float* fc1w  = (const float*)d_in[10];
    const float* fc1b  = (const float*)d_in[11];
    const float* fc2w  = (const float*)d_in[12];
    const float* fc2b  = (const float*)d_in[13];
    float* out = (float*)d_out;

    const long Mtot = 200704;
    auto pad = [](size_t b) { return (b + 255) & ~(size_t)255; };
    size_t fixed = pad((size_t)1152 * 384 * 2) + pad((size_t)384 * 384 * 2)
                 + pad((size_t)1536 * 384 * 2) + pad((size_t)384 * 1536 * 2)
                 + pad((size_t)Mtot * 384 * 2);
    // pick fewest chunks that fit: scratch = bufB(rows x 1536) + attb(rows x 384)
    int nc = 1;
    while (nc < 8) {
        size_t rows = Mtot / nc;
        if (fixed + pad(rows * 1536 * 2) + pad(rows * 384 * 2) <= ws_size) break;
        nc <<= 1;
    }
    long rows = Mtot / nc;            // rows per chunk, multiple of 128 and 49
    int  mb   = (int)(rows >> 7);     // 128-row tiles per chunk
    int  wpc  = (int)(rows / 49);     // windows per chunk

    char* ws = (char*)d_ws;
    size_t off = 0;
    auto alloc = [&](size_t bytes) { char* p = ws + off; off += (bytes + 255) & ~(size_t)255; return p; };
    unsigned short* BtQ  = (unsigned short*)alloc((size_t)1152 * 384 * 2);
    unsigned short* BtP  = (unsigned short*)alloc((size_t)384 * 384 * 2);
    unsigned short* Bt1  = (unsigned short*)alloc((size_t)1536 * 384 * 2);
    unsigned short* Bt2  = (unsigned short*)alloc((size_t)384 * 1536 * 2);
    unsigned short* xw   = (unsigned short*)alloc((size_t)Mtot * 384 * 2);   // xw, reused as h2
    unsigned short* bufB = (unsigned short*)alloc((size_t)rows * 1536 * 2);  // qkv / fc1 chunk
    unsigned short* attb = (unsigned short*)alloc((size_t)rows * 384 * 2);   // attn-out chunk

    k_transpose<<<dim3((1152 * 384 + 255) / 256), 256, 0, stream>>>(qkvw, BtQ, 384, 1152);
    k_transpose<<<dim3((384 * 384 + 255) / 256), 256, 0, stream>>>(projw, BtP, 384, 384);
    k_transpose<<<dim3((1536 * 384 + 255) / 256), 256, 0, stream>>>(fc1w, Bt1, 384, 1536);
    k_transpose<<<dim3((384 * 1536 + 255) / 256), 256, 0, stream>>>(fc2w, Bt2, 1536, 384);

    k_ln1<<<dim3(50176), 256, 0, stream>>>(x, n1g, n1b, xw);

    // attention phase
    for (int c = 0; c < nc; ++c) {
        const unsigned short* Ax = xw + (size_t)c * rows * 384;
        k_gemm<0><<<dim3(9, mb), 256, 0, stream>>>(Ax, BtQ, qkvb, bufB, nullptr, nullptr,
                                                   (int)rows, 1152, 384, 0);
        k_attn<<<dim3(12, wpc), 64, 0, stream>>>(bufB, rpb, attb, c * wpc);
        k_gemm<2><<<dim3(3, mb), 256, 0, stream>>>(attb, BtP, projb, nullptr, out, x,
                                                   (int)rows, 384, 384, (int)(c * rows));
    }

    k_ln2<<<dim3(50176), 256, 0, stream>>>(out, n2g, n2b, xw);

    // MLP phase
    for (int c = 0; c < nc; ++c) {
        const unsigned short* Ah = xw + (size_t)c * rows * 384;
        k_gemm<1><<<dim3(12, mb), 256, 0, stream>>>(Ah, Bt1, fc1b, bufB, nullptr, nullptr,
                                                    (int)rows, 1536, 384, 0);
        k_gemm<3><<<dim3(3, mb), 256, 0, stream>>>(bufB, Bt2, fc2b, nullptr, out, out,
                                                   (int)rows, 384, 1536, (int)(c * rows));
    }
}